// Round 8
// baseline (186.648 us; speedup 1.0000x reference)
//
#include <hip/hip_runtime.h>
#include <hip/hip_bf16.h>
#include <cmath>

#define BB 512
#define VV 128
#define DD 256
#define HH 4
#define DHH 64

typedef unsigned short u16;
typedef __attribute__((ext_vector_type(8))) short bf16x8;
typedef __attribute__((ext_vector_type(4))) float f32x4;

// gfx950 hardware packed fp32->bf16 (v_cvt_pk_bf16_f32), RNE.
__device__ __forceinline__ unsigned pk2(float a, float b) {
    __hip_bfloat162 h = __float22bfloat162_rn(make_float2(a, b));
    unsigned r;
    __builtin_memcpy(&r, &h, sizeof(r));
    return r;
}

// ---------------- K1: efmT[h][j][i] = adj[i,j] ? ea[i,j,:].Ew[h,:] : -inf ----
__global__ __launch_bounds__(256) void k_ef(const float* __restrict__ ea,
                                            const float* __restrict__ Ew,
                                            const int* __restrict__ adj,
                                            float* __restrict__ efmT) {
    __shared__ float tile[32][33];
    const int jt = blockIdx.x, it = blockIdx.y, h = blockIdx.z;
    const int t = threadIdx.x;
    const float e0 = Ew[h * 2], e1 = Ew[h * 2 + 1];
    const int jl = t & 31, il = t >> 5;          // read: lanes along j
    #pragma unroll
    for (int p = 0; p < 4; ++p) {
        const int i = it * 32 + p * 8 + il;
        const int j = jt * 32 + jl;
        const int ij = i * VV + j;
        float v = -INFINITY;
        if (adj[ij]) v = fmaf(ea[ij * 2 + 1], e1, ea[ij * 2] * e0);
        tile[p * 8 + il][jl] = v;
    }
    __syncthreads();
    const int i2 = t & 31, j2 = t >> 5;          // write: lanes along i
    #pragma unroll
    for (int p = 0; p < 4; ++p) {
        const int j = p * 8 + j2;
        efmT[((size_t)h * VV + jt * 32 + j) * VV + it * 32 + i2] = tile[i2][j];
    }
}

// ---------------- K2a: GEMM phase only (split diagnostic/win) ----------------
// R7's GEMM + epilogue, but WxL -> global wxT[b][c2][v] bf16 (c2 = hp*128+c)
// and masked scores -> global ss/sd[b*4 + hp*2 + head][v]. With the attention
// phase removed, the live set fits the (256,4) 128-reg class: no spills.
__global__ __launch_bounds__(256, 4) void k_gemm(
    const float* __restrict__ x, const float* __restrict__ Wm,
    const float* __restrict__ a, const int* __restrict__ mask,
    u16* __restrict__ wxT, float* __restrict__ ssg, float* __restrict__ sdg) {
    __shared__ u16 As[128 * 40];
    __shared__ u16 Bs[128 * 40];

    const int t = threadIdx.x;
    const int b = blockIdx.x, hp = blockIdx.y;
    const int w = t >> 6, L = t & 63;
    const int wr = w >> 1, wc = w & 1;
    const int lr = L & 15, lg = L >> 4;

    const int row = t >> 1, seg = t & 1;
    const float* xs = x  + ((size_t)b * VV + row) * DD + seg * 16;
    const float* ws = Wm + ((size_t)(hp * 128 + row)) * DD + seg * 16;
    u16* adst = As + row * 40 + seg * 16;
    u16* bdst = Bs + row * 40 + seg * 16;

    f32x4 acc[4][4];
    #pragma unroll
    for (int i = 0; i < 4; ++i)
        #pragma unroll
        for (int j = 0; j < 4; ++j) acc[i][j] = (f32x4){0.f, 0.f, 0.f, 0.f};

    float4 px[4];                       // A prefetch only (x is the cold side)
    #pragma unroll
    for (int q = 0; q < 4; ++q)
        px[q] = *(const float4*)(xs + q * 4);

    for (int ks = 0; ks < 8; ++ks) {
        float4 qw[4];                   // B current-tile: Wm is L2-hot
        #pragma unroll
        for (int q = 0; q < 4; ++q)
            qw[q] = *(const float4*)(ws + ks * 32 + q * 4);
        unsigned va[4], vb[4], qa[4], qb[4];
        va[0] = pk2(px[0].x, px[0].y); va[1] = pk2(px[0].z, px[0].w);
        va[2] = pk2(px[1].x, px[1].y); va[3] = pk2(px[1].z, px[1].w);
        vb[0] = pk2(px[2].x, px[2].y); vb[1] = pk2(px[2].z, px[2].w);
        vb[2] = pk2(px[3].x, px[3].y); vb[3] = pk2(px[3].z, px[3].w);
        *(bf16x8*)adst       = *(bf16x8*)&va[0];
        *(bf16x8*)(adst + 8) = *(bf16x8*)&vb[0];
        qa[0] = pk2(qw[0].x, qw[0].y); qa[1] = pk2(qw[0].z, qw[0].w);
        qa[2] = pk2(qw[1].x, qw[1].y); qa[3] = pk2(qw[1].z, qw[1].w);
        qb[0] = pk2(qw[2].x, qw[2].y); qb[1] = pk2(qw[2].z, qw[2].w);
        qb[2] = pk2(qw[3].x, qw[3].y); qb[3] = pk2(qw[3].z, qw[3].w);
        *(bf16x8*)bdst       = *(bf16x8*)&qa[0];
        *(bf16x8*)(bdst + 8) = *(bf16x8*)&qb[0];
        __syncthreads();
        if (ks < 7) {
            #pragma unroll
            for (int q = 0; q < 4; ++q)
                px[q] = *(const float4*)(xs + (ks + 1) * 32 + q * 4);
        }
        bf16x8 af[4], bfr[4];
        #pragma unroll
        for (int mi = 0; mi < 4; ++mi)
            af[mi] = *(const bf16x8*)&As[(wr * 64 + mi * 16 + lr) * 40 + lg * 8];
        #pragma unroll
        for (int ni = 0; ni < 4; ++ni)
            bfr[ni] = *(const bf16x8*)&Bs[(wc * 64 + ni * 16 + lr) * 40 + lg * 8];
        #pragma unroll
        for (int mi = 0; mi < 4; ++mi)
            #pragma unroll
            for (int ni = 0; ni < 4; ++ni)
                acc[mi][ni] = __builtin_amdgcn_mfma_f32_16x16x32_bf16(
                    af[mi], bfr[ni], acc[mi][ni], 0, 0, 0);
        __syncthreads();
    }

    // epilogue: wxT global + masked scores global
    float as_[4], ad_[4];
    #pragma unroll
    for (int ni = 0; ni < 4; ++ni) {
        as_[ni] = a[ni * 16 + lr];
        ad_[ni] = a[64 + ni * 16 + lr];
    }
    float ps[16], pd[16];
    #pragma unroll
    for (int k = 0; k < 16; ++k) { ps[k] = 0.f; pd[k] = 0.f; }
    #pragma unroll
    for (int mi = 0; mi < 4; ++mi) {
        #pragma unroll
        for (int ni = 0; ni < 4; ++ni) {
            const int c  = wc * 64 + ni * 16 + lr;    // head-pair col
            const int vb = wr * 64 + mi * 16 + lg * 4;
            unsigned o2[2];
            o2[0] = pk2(acc[mi][ni][0], acc[mi][ni][1]);
            o2[1] = pk2(acc[mi][ni][2], acc[mi][ni][3]);
            #pragma unroll
            for (int r = 0; r < 4; ++r) {
                float v = acc[mi][ni][r];
                ps[mi * 4 + r] = fmaf(v, as_[ni], ps[mi * 4 + r]);
                pd[mi * 4 + r] = fmaf(v, ad_[ni], pd[mi * 4 + r]);
            }
            u16* gw = wxT + ((size_t)(b * 256 + hp * 128 + c)) * 128 + vb;
            *(uint2*)gw = *(uint2*)&o2[0];   // L2 write-combined 8B stores
        }
    }
    #pragma unroll
    for (int k = 0; k < 16; ++k) {
        #pragma unroll
        for (int m = 1; m < 16; m <<= 1) {
            ps[k] += __shfl_xor(ps[k], m);
            pd[k] += __shfl_xor(pd[k], m);
        }
    }
    if (lr == 0) {
        const size_t so = (size_t)(b * 4 + hp * 2 + wc) * 128;  // wc == head
        #pragma unroll
        for (int mi = 0; mi < 4; ++mi)
            #pragma unroll
            for (int r = 0; r < 4; ++r) {
                int v = wr * 64 + mi * 16 + lg * 4 + r;
                bool mk = mask[b * VV + v] != 0;
                ssg[so + v] = mk ? -INFINITY : ps[mi * 4 + r];
                sdg[so + v] = mk ? -INFINITY : pd[mi * 4 + r];
            }
    }
}

// ---------------- K2b: attention phase only — ZERO LDS, ZERO barriers -------
// P computed straight into MFMA A-fragments (as before); B-fragments loaded
// directly from global wxT (16B/lane, lanes cover whole 64B lines, L2-hot);
// scores from global; rden via in-wave __shfl broadcast instead of LDS.
// Barrier-free waves at 16 waves/CU overlap their own load latency.
__global__ __launch_bounds__(256, 4) void k_attn(
    const u16* __restrict__ wxT, const float* __restrict__ ssg,
    const float* __restrict__ sdg, const float* __restrict__ efmT,
    float* __restrict__ out) {
    const int t = threadIdx.x;
    const int b = blockIdx.x, hp = blockIdx.y;
    const int w = t >> 6, L = t & 63;
    const int lr = L & 15, lg = L >> 4;

    const int j0 = w * 32 + lr;          // mi=0 row; mi=1 row = j0+16
    for (int hl = 0; hl < 2; ++hl) {
        const int h = hp * 2 + hl;
        const float* ssp = ssg + (size_t)(b * 4 + hp * 2 + hl) * 128;
        const float* sdp = sdg + (size_t)(b * 4 + hp * 2 + hl) * 128;
        const float sdj0 = sdp[j0];
        const float sdj1 = sdp[j0 + 16];
        const float* ef0 = efmT + ((size_t)h * VV + j0) * VV;
        const float* ef1 = ef0 + 16 * VV;
        bf16x8 af2[2][4];
        float ps0 = 0.f, ps1 = 0.f;
        #pragma unroll
        for (int ks = 0; ks < 4; ++ks) {
            const int i0 = ks * 32 + lg * 8;
            float sv[8], ev0[8], ev1[8];
            *(float4*)&sv[0]  = *(const float4*)(ssp + i0);
            *(float4*)&sv[4]  = *(const float4*)(ssp + i0 + 4);
            *(float4*)&ev0[0] = *(const float4*)(ef0 + i0);
            *(float4*)&ev0[4] = *(const float4*)(ef0 + i0 + 4);
            *(float4*)&ev1[0] = *(const float4*)(ef1 + i0);
            *(float4*)&ev1[4] = *(const float4*)(ef1 + i0 + 4);
            float p0[8], p1[8];
            #pragma unroll
            for (int u = 0; u < 8; ++u) {
                float e0 = sv[u] + sdj0 + ev0[u];
                float e1 = sv[u] + sdj1 + ev1[u];
                e0 = fmaxf(e0, 0.2f * e0);     // leaky relu
                e1 = fmaxf(e1, 0.2f * e1);
                p0[u] = __expf(e0); ps0 += p0[u];   // exp(-inf)=0 masks
                p1[u] = __expf(e1); ps1 += p1[u];
            }
            unsigned* a0 = (unsigned*)&af2[0][ks];
            unsigned* a1 = (unsigned*)&af2[1][ks];
            a0[0] = pk2(p0[0], p0[1]); a0[1] = pk2(p0[2], p0[3]);
            a0[2] = pk2(p0[4], p0[5]); a0[3] = pk2(p0[6], p0[7]);
            a1[0] = pk2(p1[0], p1[1]); a1[1] = pk2(p1[2], p1[3]);
            a1[2] = pk2(p1[4], p1[5]); a1[3] = pk2(p1[6], p1[7]);
        }
        // denom: combine lg-slices (bits 4,5); afterwards EVERY lane holds
        // the full sum for its j0 row (and j0+16 via ps1).
        ps0 += __shfl_xor(ps0, 16); ps0 += __shfl_xor(ps0, 32);
        ps1 += __shfl_xor(ps1, 16); ps1 += __shfl_xor(ps1, 32);
        const float rdv0 = ps0 > 0.f ? 1.f / ps0 : 0.f;   // rows w*32+lr
        const float rdv1 = ps1 > 0.f ? 1.f / ps1 : 0.f;   // rows w*32+16+lr

        f32x4 acc2[2][4];
        #pragma unroll
        for (int mi = 0; mi < 2; ++mi)
            #pragma unroll
            for (int ni = 0; ni < 4; ++ni) acc2[mi][ni] = (f32x4){0.f, 0.f, 0.f, 0.f};
        const u16* wb = wxT + ((size_t)(b * 256 + hp * 128 + hl * 64 + lr)) * 128;
        #pragma unroll
        for (int ks = 0; ks < 4; ++ks) {
            const int kk = ks * 32 + lg * 8;
            #pragma unroll
            for (int ni = 0; ni < 4; ++ni) {
                bf16x8 bf2 = *(const bf16x8*)(wb + (size_t)(ni * 16) * 128 + kk);
                acc2[0][ni] = __builtin_amdgcn_mfma_f32_16x16x32_bf16(
                    af2[0][ks], bf2, acc2[0][ni], 0, 0, 0);
                acc2[1][ni] = __builtin_amdgcn_mfma_f32_16x16x32_bf16(
                    af2[1][ks], bf2, acc2[1][ni], 0, 0, 0);
            }
        }

        #pragma unroll
        for (int mi = 0; mi < 2; ++mi) {
            // rden for rows jb..jb+3: row&15 = lg*4+r, held by lane lr=lg*4+r
            // of the same 16-lane group; mi picks rdv0/rdv1.
            float rd[4];
            #pragma unroll
            for (int r = 0; r < 4; ++r)
                rd[r] = __shfl(mi == 0 ? rdv0 : rdv1, lg * 4 + r, 16);
            #pragma unroll
            for (int ni = 0; ni < 4; ++ni) {
                const int dcol = ni * 16 + lr;
                const int jb   = w * 32 + mi * 16 + lg * 4;
                float* op = out + ((size_t)b * VV + jb) * DD + h * DHH + dcol;
                #pragma unroll
                for (int r = 0; r < 4; ++r) {
                    float v = acc2[mi][ni][r] * rd[r];
                    v = v > 0.f ? v : (__expf(v) - 1.0f);   // ELU
                    op[(size_t)r * DD] = v;
                }
            }
        }
    }
}

// ---------------- Fallback: R7 fused kernel (used if workspace too small) ---
__global__ __launch_bounds__(256, 4) void k_fused(
    const float* __restrict__ x, const float* __restrict__ Wm,
    const float* __restrict__ a, const float* __restrict__ efmT,
    const int* __restrict__ mask, float* __restrict__ out) {
    __shared__ u16 ubuf[128 * 136];
    __shared__ float ssl[256], sdl[256], rden[2][128];
    __shared__ int mkl[128];

    u16* As  = ubuf;
    u16* Bs  = ubuf + 128 * 40;
    u16* WxL = ubuf;

    const int t = threadIdx.x;
    const int b = blockIdx.x, hp = blockIdx.y;
    const int w = t >> 6, L = t & 63;
    const int wr = w >> 1, wc = w & 1;
    const int lr = L & 15, lg = L >> 4;

    if (t < 128) mkl[t] = mask[b * VV + t];

    const int row = t >> 1, seg = t & 1;
    const float* xs = x  + ((size_t)b * VV + row) * DD + seg * 16;
    const float* ws = Wm + ((size_t)(hp * 128 + row)) * DD + seg * 16;
    u16* adst = As + row * 40 + seg * 16;
    u16* bdst = Bs + row * 40 + seg * 16;

    f32x4 acc[4][4];
    #pragma unroll
    for (int i = 0; i < 4; ++i)
        #pragma unroll
        for (int j = 0; j < 4; ++j) acc[i][j] = (f32x4){0.f, 0.f, 0.f, 0.f};

    float4 px[4];
    #pragma unroll
    for (int q = 0; q < 4; ++q) px[q] = *(const float4*)(xs + q * 4);

    for (int ks = 0; ks < 8; ++ks) {
        float4 qw[4];
        #pragma unroll
        for (int q = 0; q < 4; ++q)
            qw[q] = *(const float4*)(ws + ks * 32 + q * 4);
        unsigned va[4], vb[4], qa[4], qb[4];
        va[0] = pk2(px[0].x, px[0].y); va[1] = pk2(px[0].z, px[0].w);
        va[2] = pk2(px[1].x, px[1].y); va[3] = pk2(px[1].z, px[1].w);
        vb[0] = pk2(px[2].x, px[2].y); vb[1] = pk2(px[2].z, px[2].w);
        vb[2] = pk2(px[3].x, px[3].y); vb[3] = pk2(px[3].z, px[3].w);
        *(bf16x8*)adst       = *(bf16x8*)&va[0];
        *(bf16x8*)(adst + 8) = *(bf16x8*)&vb[0];
        qa[0] = pk2(qw[0].x, qw[0].y); qa[1] = pk2(qw[0].z, qw[0].w);
        qa[2] = pk2(qw[1].x, qw[1].y); qa[3] = pk2(qw[1].z, qw[1].w);
        qb[0] = pk2(qw[2].x, qw[2].y); qb[1] = pk2(qw[2].z, qw[2].w);
        qb[2] = pk2(qw[3].x, qw[3].y); qb[3] = pk2(qw[3].z, qw[3].w);
        *(bf16x8*)bdst       = *(bf16x8*)&qa[0];
        *(bf16x8*)(bdst + 8) = *(bf16x8*)&qb[0];
        __syncthreads();
        if (ks < 7) {
            #pragma unroll
            for (int q = 0; q < 4; ++q)
                px[q] = *(const float4*)(xs + (ks + 1) * 32 + q * 4);
        }
        bf16x8 af[4], bfr[4];
        #pragma unroll
        for (int mi = 0; mi < 4; ++mi)
            af[mi] = *(const bf16x8*)&As[(wr * 64 + mi * 16 + lr) * 40 + lg * 8];
        #pragma unroll
        for (int ni = 0; ni < 4; ++ni)
            bfr[ni] = *(const bf16x8*)&Bs[(wc * 64 + ni * 16 + lr) * 40 + lg * 8];
        #pragma unroll
        for (int mi = 0; mi < 4; ++mi)
            #pragma unroll
            for (int ni = 0; ni < 4; ++ni)
                acc[mi][ni] = __builtin_amdgcn_mfma_f32_16x16x32_bf16(
                    af[mi], bfr[ni], acc[mi][ni], 0, 0, 0);
        __syncthreads();
    }

    float as_[4], ad_[4];
    #pragma unroll
    for (int ni = 0; ni < 4; ++ni) {
        as_[ni] = a[ni * 16 + lr];
        ad_[ni] = a[64 + ni * 16 + lr];
    }
    float ps[16], pd[16];
    #pragma unroll
    for (int k = 0; k < 16; ++k) { ps[k] = 0.f; pd[k] = 0.f; }
    #pragma unroll
    for (int mi = 0; mi < 4; ++mi) {
        #pragma unroll
        for (int ni = 0; ni < 4; ++ni) {
            const int c  = wc * 64 + ni * 16 + lr;
            const int vb = wr * 64 + mi * 16 + lg * 4;
            unsigned o2[2];
            o2[0] = pk2(acc[mi][ni][0], acc[mi][ni][1]);
            o2[1] = pk2(acc[mi][ni][2], acc[mi][ni][3]);
            #pragma unroll
            for (int r = 0; r < 4; ++r) {
                float v = acc[mi][ni][r];
                ps[mi * 4 + r] = fmaf(v, as_[ni], ps[mi * 4 + r]);
                pd[mi * 4 + r] = fmaf(v, ad_[ni], pd[mi * 4 + r]);
            }
            *(uint2*)&WxL[c * 136 + vb] = *(uint2*)&o2[0];
        }
    }
    #pragma unroll
    for (int k = 0; k < 16; ++k) {
        #pragma unroll
        for (int m = 1; m < 16; m <<= 1) {
            ps[k] += __shfl_xor(ps[k], m);
            pd[k] += __shfl_xor(pd[k], m);
        }
    }
    if (lr == 0) {
        #pragma unroll
        for (int mi = 0; mi < 4; ++mi)
            #pragma unroll
            for (int r = 0; r < 4; ++r) {
                int v = wr * 64 + mi * 16 + lg * 4 + r;
                bool mk = mkl[v] != 0;
                ssl[wc * 128 + v] = mk ? -INFINITY : ps[mi * 4 + r];
                sdl[wc * 128 + v] = mk ? -INFINITY : pd[mi * 4 + r];
            }
    }
    __syncthreads();

    const int j0 = w * 32 + lr;
    for (int hl = 0; hl < 2; ++hl) {
        const int h = hp * 2 + hl;
        const float sdj0 = sdl[hl * 128 + j0];
        const float sdj1 = sdl[hl * 128 + j0 + 16];
        const float* ef0 = efmT + ((size_t)h * VV + j0) * VV;
        const float* ef1 = ef0 + 16 * VV;
        bf16x8 af2[2][4];
        float ps0 = 0.f, ps1 = 0.f;
        #pragma unroll
        for (int ks = 0; ks < 4; ++ks) {
            const int i0 = ks * 32 + lg * 8;
            float sv[8], ev0[8], ev1[8];
            *(float4*)&sv[0]  = *(const float4*)&ssl[hl * 128 + i0];
            *(float4*)&sv[4]  = *(const float4*)&ssl[hl * 128 + i0 + 4];
            *(float4*)&ev0[0] = *(const float4*)(ef0 + i0);
            *(float4*)&ev0[4] = *(const float4*)(ef0 + i0 + 4);
            *(float4*)&ev1[0] = *(const float4*)(ef1 + i0);
            *(float4*)&ev1[4] = *(const float4*)(ef1 + i0 + 4);
            float p0[8], p1[8];
            #pragma unroll
            for (int u = 0; u < 8; ++u) {
                float e0 = sv[u] + sdj0 + ev0[u];
                float e1 = sv[u] + sdj1 + ev1[u];
                e0 = fmaxf(e0, 0.2f * e0);
                e1 = fmaxf(e1, 0.2f * e1);
                p0[u] = __expf(e0); ps0 += p0[u];
                p1[u] = __expf(e1); ps1 += p1[u];
            }
            unsigned* a0 = (unsigned*)&af2[0][ks];
            unsigned* a1 = (unsigned*)&af2[1][ks];
            a0[0] = pk2(p0[0], p0[1]); a0[1] = pk2(p0[2], p0[3]);
            a0[2] = pk2(p0[4], p0[5]); a0[3] = pk2(p0[6], p0[7]);
            a1[0] = pk2(p1[0], p1[1]); a1[1] = pk2(p1[2], p1[3]);
            a1[2] = pk2(p1[4], p1[5]); a1[3] = pk2(p1[6], p1[7]);
        }
        ps0 += __shfl_xor(ps0, 16); ps0 += __shfl_xor(ps0, 32);
        ps1 += __shfl_xor(ps1, 16); ps1 += __shfl_xor(ps1, 32);
        if (lg == 0) {
            rden[hl][j0]      = ps0 > 0.f ? 1.f / ps0 : 0.f;
            rden[hl][j0 + 16] = ps1 > 0.f ? 1.f / ps1 : 0.f;
        }
        f32x4 acc2[2][4];
        #pragma unroll
        for (int mi = 0; mi < 2; ++mi)
            #pragma unroll
            for (int ni = 0; ni < 4; ++ni) acc2[mi][ni] = (f32x4){0.f, 0.f, 0.f, 0.f};
        #pragma unroll
        for (int ks = 0; ks < 4; ++ks) {
            const int kk = ks * 32 + lg * 8;
            #pragma unroll
            for (int ni = 0; ni < 4; ++ni) {
                bf16x8 bf2 = *(const bf16x8*)&WxL[(hl * 64 + ni * 16 + lr) * 136 + kk];
                acc2[0][ni] = __builtin_amdgcn_mfma_f32_16x16x32_bf16(
                    af2[0][ks], bf2, acc2[0][ni], 0, 0, 0);
                acc2[1][ni] = __builtin_amdgcn_mfma_f32_16x16x32_bf16(
                    af2[1][ks], bf2, acc2[1][ni], 0, 0, 0);
            }
        }
        #pragma unroll
        for (int mi = 0; mi < 2; ++mi)
            #pragma unroll
            for (int ni = 0; ni < 4; ++ni) {
                const int dcol = ni * 16 + lr;
                const int jb   = w * 32 + mi * 16 + lg * 4;
                float* op = out + ((size_t)b * VV + jb) * DD + h * DHH + dcol;
                #pragma unroll
                for (int r = 0; r < 4; ++r) {
                    float v = acc2[mi][ni][r] * rden[hl][jb + r];
                    v = v > 0.f ? v : (__expf(v) - 1.0f);
                    op[(size_t)r * DD] = v;
                }
            }
    }
}

extern "C" void kernel_launch(void* const* d_in, const int* in_sizes, int n_in,
                              void* d_out, int out_size, void* d_ws, size_t ws_size,
                              hipStream_t stream) {
    const float* x    = (const float*)d_in[0];
    const int*   adj  = (const int*)d_in[1];
    const float* ea   = (const float*)d_in[2];
    const int*   mask = (const int*)d_in[3];
    const float* Wm   = (const float*)d_in[4];
    const float* a    = (const float*)d_in[5];
    const float* Ew   = (const float*)d_in[6];
    float* out = (float*)d_out;

    char* ws = (char*)d_ws;
    float* efmT = (float*)ws;                          // 256 KiB
    const size_t EFM_SZ = (size_t)HH * VV * VV * 4;    // 262144
    const size_t WXT_SZ = (size_t)BB * 256 * 128 * 2;  // 16 MiB
    const size_t SS_SZ  = (size_t)BB * 4 * 128 * 4;    // 1 MiB
    const size_t NEED   = EFM_SZ + WXT_SZ + 2 * SS_SZ;

    k_ef<<<dim3(4, 4, HH), 256, 0, stream>>>(ea, Ew, adj, efmT);

    if (ws_size >= NEED) {
        u16*   wxT = (u16*)(ws + EFM_SZ);
        float* ssg = (float*)(ws + EFM_SZ + WXT_SZ);
        float* sdg = (float*)(ws + EFM_SZ + WXT_SZ + SS_SZ);
        k_gemm<<<dim3(BB, 2), 256, 0, stream>>>(x, Wm, a, mask, wxT, ssg, sdg);
        k_attn<<<dim3(BB, 2), 256, 0, stream>>>(wxT, ssg, sdg, efmT, out);
    } else {
        k_fused<<<dim3(BB, 2), 256, 0, stream>>>(x, Wm, a, efmT, mask, out);
    }
}

// Round 9
// 165.497 us; speedup vs baseline: 1.1278x; 1.1278x over previous
//
#include <hip/hip_runtime.h>
#include <hip/hip_bf16.h>
#include <cmath>

#define BB 512
#define VV 128
#define DD 256
#define HH 4
#define DHH 64

typedef unsigned short u16;
typedef __attribute__((ext_vector_type(8))) short bf16x8;
typedef __attribute__((ext_vector_type(4))) float f32x4;

// gfx950 hardware packed fp32->bf16 (v_cvt_pk_bf16_f32), RNE.
__device__ __forceinline__ unsigned pk2(float a, float b) {
    __hip_bfloat162 h = __float22bfloat162_rn(make_float2(a, b));
    unsigned r;
    __builtin_memcpy(&r, &h, sizeof(r));
    return r;
}

// ---------------- K1: efmT[h][j][i] = adj[i,j] ? ea[i,j,:].Ew[h,:] : -inf ----
// LDS-transpose: reads coalesced along j, writes coalesced along i. 64 blocks.
__global__ __launch_bounds__(256) void k_ef(const float* __restrict__ ea,
                                            const float* __restrict__ Ew,
                                            const int* __restrict__ adj,
                                            float* __restrict__ efmT) {
    __shared__ float tile[32][33];
    const int jt = blockIdx.x, it = blockIdx.y, h = blockIdx.z;
    const int t = threadIdx.x;
    const float e0 = Ew[h * 2], e1 = Ew[h * 2 + 1];
    const int jl = t & 31, il = t >> 5;          // read: lanes along j
    #pragma unroll
    for (int p = 0; p < 4; ++p) {
        const int i = it * 32 + p * 8 + il;
        const int j = jt * 32 + jl;
        const int ij = i * VV + j;
        float v = -INFINITY;
        if (adj[ij]) v = fmaf(ea[ij * 2 + 1], e1, ea[ij * 2] * e0);
        tile[p * 8 + il][jl] = v;
    }
    __syncthreads();
    const int i2 = t & 31, j2 = t >> 5;          // write: lanes along i
    #pragma unroll
    for (int p = 0; p < 4; ++p) {
        const int j = p * 8 + j2;
        efmT[((size_t)h * VV + jt * 32 + j) * VV + it * 32 + i2] = tile[i2][j];
    }
}

// ---------------- K2: fully fused GAT per (b, head-pair) ----------------
// EXACT R7 structure with ONE mechanism changed: the K-loop barriers are raw
// s_barrier instead of __syncthreads. __syncthreads lowers to
// `s_waitcnt vmcnt(0) lgkmcnt(0); s_barrier` — the vmcnt(0) drain force-
// completes reg-destined global loads at every barrier, which NULLIFIED every
// cross-barrier register prefetch in R1-R7 (explains R7==R1 when pw-prefetch
// was removed, R5's dead double-buffer, and the split k_gemm's 85% stall at
// 1.9 TB/s). Raw barrier scheme:
//   staging ds_writes -> issue next px loads -> s_waitcnt lgkmcnt(0) ->
//   s_barrier -> frag ds_reads + MFMA -> s_barrier (no wait needed: frag
//   reads are retired by the compiler's own lgkm waits before their MFMAs)
// so px loads legitimately stay in flight across BOTH barriers (~500+cy
// cover) instead of being drained after ~80cy.
// LDS correctness: producer lgkmcnt(0)+barrier makes ds_writes visible before
// any frag read; consumer reads retire before barrier-2, so next-iter writes
// can't race them. Reg-loads have no cross-thread visibility obligations.
__global__ __launch_bounds__(256, 4) void k_fused(
    const float* __restrict__ x, const float* __restrict__ Wm,
    const float* __restrict__ a, const float* __restrict__ efmT,
    const int* __restrict__ mask, float* __restrict__ out) {
    __shared__ u16 ubuf[128 * 136];     // GEMM: As+Bs (20.5KB); attn: WxL 34.8KB
    __shared__ float ssl[256], sdl[256], rden[2][128];
    __shared__ int mkl[128];

    u16* As  = ubuf;                    // [128][40]
    u16* Bs  = ubuf + 128 * 40;        // [128][40]
    u16* WxL = ubuf;                    // [c][v] stride 136 (post-GEMM)

    const int t = threadIdx.x;
    const int b = blockIdx.x, hp = blockIdx.y;
    const int w = t >> 6, L = t & 63;
    const int wr = w >> 1, wc = w & 1;
    const int lr = L & 15, lg = L >> 4;

    if (t < 128) mkl[t] = mask[b * VV + t];

    // ---- GEMM phase ----
    const int row = t >> 1, seg = t & 1;
    const float* xs = x  + ((size_t)b * VV + row) * DD + seg * 16;
    const float* ws = Wm + ((size_t)(hp * 128 + row)) * DD + seg * 16;
    u16* adst = As + row * 40 + seg * 16;
    u16* bdst = Bs + row * 40 + seg * 16;

    f32x4 acc[4][4];
    #pragma unroll
    for (int i = 0; i < 4; ++i)
        #pragma unroll
        for (int j = 0; j < 4; ++j) acc[i][j] = (f32x4){0.f, 0.f, 0.f, 0.f};

    float4 px[4];                       // A prefetch (x is the cold HBM side)
    #pragma unroll
    for (int q = 0; q < 4; ++q)
        px[q] = *(const float4*)(xs + q * 4);

    for (int ks = 0; ks < 8; ++ks) {
        // B loads for the CURRENT tile: Wm is L2-hot (read by all 1024 blocks)
        float4 qw[4];
        #pragma unroll
        for (int q = 0; q < 4; ++q)
            qw[q] = *(const float4*)(ws + ks * 32 + q * 4);
        unsigned va[4], vb[4], qa[4], qb[4];
        va[0] = pk2(px[0].x, px[0].y); va[1] = pk2(px[0].z, px[0].w);
        va[2] = pk2(px[1].x, px[1].y); va[3] = pk2(px[1].z, px[1].w);
        vb[0] = pk2(px[2].x, px[2].y); vb[1] = pk2(px[2].z, px[2].w);
        vb[2] = pk2(px[3].x, px[3].y); vb[3] = pk2(px[3].z, px[3].w);
        *(bf16x8*)adst       = *(bf16x8*)&va[0];
        *(bf16x8*)(adst + 8) = *(bf16x8*)&vb[0];
        qa[0] = pk2(qw[0].x, qw[0].y); qa[1] = pk2(qw[0].z, qw[0].w);
        qa[2] = pk2(qw[1].x, qw[1].y); qa[3] = pk2(qw[1].z, qw[1].w);
        qb[0] = pk2(qw[2].x, qw[2].y); qb[1] = pk2(qw[2].z, qw[2].w);
        qb[2] = pk2(qw[3].x, qw[3].y); qb[3] = pk2(qw[3].z, qw[3].w);
        *(bf16x8*)bdst       = *(bf16x8*)&qa[0];
        *(bf16x8*)(bdst + 8) = *(bf16x8*)&qb[0];
        if (ks < 7) {   // issue next A-tile loads NOW: they stay in flight
            #pragma unroll // across both raw barriers until next iter's cvt
            for (int q = 0; q < 4; ++q)
                px[q] = *(const float4*)(xs + (ks + 1) * 32 + q * 4);
        }
        // producer side: ds_writes visible to the group; vmcnt NOT drained
        asm volatile("s_waitcnt lgkmcnt(0)" ::: "memory");
        __builtin_amdgcn_s_barrier();
        bf16x8 af[4], bfr[4];
        #pragma unroll
        for (int mi = 0; mi < 4; ++mi)
            af[mi] = *(const bf16x8*)&As[(wr * 64 + mi * 16 + lr) * 40 + lg * 8];
        #pragma unroll
        for (int ni = 0; ni < 4; ++ni)
            bfr[ni] = *(const bf16x8*)&Bs[(wc * 64 + ni * 16 + lr) * 40 + lg * 8];
        #pragma unroll
        for (int mi = 0; mi < 4; ++mi)
            #pragma unroll
            for (int ni = 0; ni < 4; ++ni)
                acc[mi][ni] = __builtin_amdgcn_mfma_f32_16x16x32_bf16(
                    af[mi], bfr[ni], acc[mi][ni], 0, 0, 0);
        // frag reads retired (compiler lgkm waits precede the MFMAs) ->
        // next iter's ds_writes can't race them past this barrier.
        __builtin_amdgcn_s_barrier();
        asm volatile("" ::: "memory");
    }

    // ---- GEMM epilogue: WxL[c][v] bf16 (union over As/Bs) + masked scores ----
    float as_[4], ad_[4];
    #pragma unroll
    for (int ni = 0; ni < 4; ++ni) {
        as_[ni] = a[ni * 16 + lr];
        ad_[ni] = a[64 + ni * 16 + lr];
    }
    float ps[16], pd[16];
    #pragma unroll
    for (int k = 0; k < 16; ++k) { ps[k] = 0.f; pd[k] = 0.f; }
    #pragma unroll
    for (int mi = 0; mi < 4; ++mi) {
        #pragma unroll
        for (int ni = 0; ni < 4; ++ni) {
            const int c  = wc * 64 + ni * 16 + lr;    // hl*64 + d
            const int vb = wr * 64 + mi * 16 + lg * 4;
            unsigned o2[2];
            o2[0] = pk2(acc[mi][ni][0], acc[mi][ni][1]);
            o2[1] = pk2(acc[mi][ni][2], acc[mi][ni][3]);
            #pragma unroll
            for (int r = 0; r < 4; ++r) {
                float v = acc[mi][ni][r];
                ps[mi * 4 + r] = fmaf(v, as_[ni], ps[mi * 4 + r]);
                pd[mi * 4 + r] = fmaf(v, ad_[ni], pd[mi * 4 + r]);
            }
            *(uint2*)&WxL[c * 136 + vb] = *(uint2*)&o2[0];   // ds_write_b64
        }
    }
    #pragma unroll
    for (int k = 0; k < 16; ++k) {
        #pragma unroll
        for (int m = 1; m < 16; m <<= 1) {
            ps[k] += __shfl_xor(ps[k], m);
            pd[k] += __shfl_xor(pd[k], m);
        }
    }
    if (lr == 0) {
        #pragma unroll
        for (int mi = 0; mi < 4; ++mi)
            #pragma unroll
            for (int r = 0; r < 4; ++r) {
                int v = wr * 64 + mi * 16 + lg * 4 + r;
                bool mk = mkl[v] != 0;
                ssl[wc * 128 + v] = mk ? -INFINITY : ps[mi * 4 + r];
                sdl[wc * 128 + v] = mk ? -INFINITY : pd[mi * 4 + r];
            }
    }
    __syncthreads();   // full sync: WxL + scores ready for all waves

    // ---- Attention: P straight into A-fragments, per head ----
    const int j0 = w * 32 + lr;          // mi=0 row; mi=1 row = j0+16
    for (int hl = 0; hl < 2; ++hl) {
        const int h = hp * 2 + hl;
        const float sdj0 = sdl[hl * 128 + j0];
        const float sdj1 = sdl[hl * 128 + j0 + 16];
        const float* ef0 = efmT + ((size_t)h * VV + j0) * VV;
        const float* ef1 = ef0 + 16 * VV;
        bf16x8 af2[2][4];
        float ps0 = 0.f, ps1 = 0.f;
        #pragma unroll
        for (int ks = 0; ks < 4; ++ks) {
            const int i0 = ks * 32 + lg * 8;
            float sv[8], ev0[8], ev1[8];
            *(float4*)&sv[0]  = *(const float4*)&ssl[hl * 128 + i0];
            *(float4*)&sv[4]  = *(const float4*)&ssl[hl * 128 + i0 + 4];
            *(float4*)&ev0[0] = *(const float4*)(ef0 + i0);
            *(float4*)&ev0[4] = *(const float4*)(ef0 + i0 + 4);
            *(float4*)&ev1[0] = *(const float4*)(ef1 + i0);
            *(float4*)&ev1[4] = *(const float4*)(ef1 + i0 + 4);
            float p0[8], p1[8];
            #pragma unroll
            for (int u = 0; u < 8; ++u) {
                float e0 = sv[u] + sdj0 + ev0[u];
                float e1 = sv[u] + sdj1 + ev1[u];
                e0 = fmaxf(e0, 0.2f * e0);     // leaky relu
                e1 = fmaxf(e1, 0.2f * e1);
                p0[u] = __expf(e0); ps0 += p0[u];   // exp(-inf)=0 masks
                p1[u] = __expf(e1); ps1 += p1[u];
            }
            unsigned* a0 = (unsigned*)&af2[0][ks];
            unsigned* a1 = (unsigned*)&af2[1][ks];
            a0[0] = pk2(p0[0], p0[1]); a0[1] = pk2(p0[2], p0[3]);
            a0[2] = pk2(p0[4], p0[5]); a0[3] = pk2(p0[6], p0[7]);
            a1[0] = pk2(p1[0], p1[1]); a1[1] = pk2(p1[2], p1[3]);
            a1[2] = pk2(p1[4], p1[5]); a1[3] = pk2(p1[6], p1[7]);
        }
        // denom over all 128 i: lanes sharing j differ only in lg (bits 4,5)
        ps0 += __shfl_xor(ps0, 16); ps0 += __shfl_xor(ps0, 32);
        ps1 += __shfl_xor(ps1, 16); ps1 += __shfl_xor(ps1, 32);
        if (lg == 0) {
            rden[hl][j0]      = ps0 > 0.f ? 1.f / ps0 : 0.f;
            rden[hl][j0 + 16] = ps1 > 0.f ? 1.f / ps1 : 0.f;
        }
        // rden rows w*32..w*32+31: written and read by THIS wave only.

        f32x4 acc2[2][4];
        #pragma unroll
        for (int mi = 0; mi < 2; ++mi)
            #pragma unroll
            for (int ni = 0; ni < 4; ++ni) acc2[mi][ni] = (f32x4){0.f, 0.f, 0.f, 0.f};
        #pragma unroll
        for (int ks = 0; ks < 4; ++ks) {
            const int kk = ks * 32 + lg * 8;
            #pragma unroll
            for (int ni = 0; ni < 4; ++ni) {
                bf16x8 bf2 = *(const bf16x8*)&WxL[(hl * 64 + ni * 16 + lr) * 136 + kk];
                acc2[0][ni] = __builtin_amdgcn_mfma_f32_16x16x32_bf16(
                    af2[0][ks], bf2, acc2[0][ni], 0, 0, 0);
                acc2[1][ni] = __builtin_amdgcn_mfma_f32_16x16x32_bf16(
                    af2[1][ks], bf2, acc2[1][ni], 0, 0, 0);
            }
        }

        #pragma unroll
        for (int mi = 0; mi < 2; ++mi)
            #pragma unroll
            for (int ni = 0; ni < 4; ++ni) {
                const int dcol = ni * 16 + lr;
                const int jb   = w * 32 + mi * 16 + lg * 4;
                float* op = out + ((size_t)b * VV + jb) * DD + h * DHH + dcol;
                #pragma unroll
                for (int r = 0; r < 4; ++r) {
                    float v = acc2[mi][ni][r] * rden[hl][jb + r];
                    // ELU: __expf(v)-1 (2 insts) instead of OCML expm1f.
                    v = v > 0.f ? v : (__expf(v) - 1.0f);
                    op[(size_t)r * DD] = v;
                }
            }
    }
}

extern "C" void kernel_launch(void* const* d_in, const int* in_sizes, int n_in,
                              void* d_out, int out_size, void* d_ws, size_t ws_size,
                              hipStream_t stream) {
    const float* x    = (const float*)d_in[0];
    const int*   adj  = (const int*)d_in[1];
    const float* ea   = (const float*)d_in[2];
    const int*   mask = (const int*)d_in[3];
    const float* Wm   = (const float*)d_in[4];
    const float* a    = (const float*)d_in[5];
    const float* Ew   = (const float*)d_in[6];
    float* out = (float*)d_out;

    float* efmT = (float*)d_ws;   // [H][j][i] fp32, 256 KiB

    k_ef<<<dim3(4, 4, HH), 256, 0, stream>>>(ea, Ew, adj, efmT);
    k_fused<<<dim3(BB, 2), 256, 0, stream>>>(x, Wm, a, efmT, mask, out);
}

// Round 10
// 149.097 us; speedup vs baseline: 1.2519x; 1.1100x over previous
//
#include <hip/hip_runtime.h>
#include <hip/hip_bf16.h>
#include <cmath>

#define BB 512
#define VV 128
#define DD 256
#define HH 4
#define DHH 64

typedef unsigned short u16;
typedef __attribute__((ext_vector_type(8))) short bf16x8;
typedef __attribute__((ext_vector_type(4))) float f32x4;

// gfx950 hardware packed fp32->bf16 (v_cvt_pk_bf16_f32), RNE.
__device__ __forceinline__ unsigned pk2(float a, float b) {
    __hip_bfloat162 h = __float22bfloat162_rn(make_float2(a, b));
    unsigned r;
    __builtin_memcpy(&r, &h, sizeof(r));
    return r;
}

// Async global->LDS DMA, 16B/lane. LDS dest is wave-uniform base + lane*16
// (hardware rule); global src is per-lane. Tracked by vmcnt; __syncthreads'
// drain completes it before any cross-thread read.
__device__ __forceinline__ void gld16(const float* g, float* lds) {
    __builtin_amdgcn_global_load_lds(
        (const __attribute__((address_space(1))) void*)g,
        (__attribute__((address_space(3))) void*)lds, 16, 0, 0);
}

// ---------------- K1: efmT[h][j][i] = adj[i,j] ? ea[i,j,:].Ew[h,:] : -inf ----
// LDS-transpose: reads coalesced along j, writes coalesced along i. 64 blocks.
__global__ __launch_bounds__(256) void k_ef(const float* __restrict__ ea,
                                            const float* __restrict__ Ew,
                                            const int* __restrict__ adj,
                                            float* __restrict__ efmT) {
    __shared__ float tile[32][33];
    const int jt = blockIdx.x, it = blockIdx.y, h = blockIdx.z;
    const int t = threadIdx.x;
    const float e0 = Ew[h * 2], e1 = Ew[h * 2 + 1];
    const int jl = t & 31, il = t >> 5;          // read: lanes along j
    #pragma unroll
    for (int p = 0; p < 4; ++p) {
        const int i = it * 32 + p * 8 + il;
        const int j = jt * 32 + jl;
        const int ij = i * VV + j;
        float v = -INFINITY;
        if (adj[ij]) v = fmaf(ea[ij * 2 + 1], e1, ea[ij * 2] * e0);
        tile[p * 8 + il][jl] = v;
    }
    __syncthreads();
    const int i2 = t & 31, j2 = t >> 5;          // write: lanes along i
    #pragma unroll
    for (int p = 0; p < 4; ++p) {
        const int j = p * 8 + j2;
        efmT[((size_t)h * VV + jt * 32 + j) * VV + it * 32 + i2] = tile[i2][j];
    }
}

// ---------------- K2: fully fused GAT per (b, head-pair) ----------------
// R7 structure (128x128 tile, grid (b,hp), (256,4), 2 barriers/K-step,
// plain __syncthreads — R9 proved inline-asm barriers wreck codegen) with the
// GEMM staging replaced by global_load_lds DMA of the fp32 tiles:
//  - deletes the load->VGPR->cvt->ds_write chain (px/qw regs, dependent-chain
//    stall, staging VALU). All 8 staging DMAs issue instantly, zero consumers;
//    the barrier drain covers all of them with ONE latency, and 4 blocks/CU
//    overlap covers that. (m97 mechanism: +69% on this structure w/ bf16.)
//  - bf16 convert moves to fragment prep (fp32 ds_read_b128 x2 + 4 pk2/frag).
//  - DMA writes LDS linearly (no padding allowed) => linear [128][32] fp32
//    tile would be 16-way bank-conflicted on b128 reads. Fix: T2 XOR swizzle,
//    BOTH sides: source chunk (L&7)^((L>>3)&7) per lane (a per-lane constant)
//    and read offset ^((lr&7)<<2) dwords. 8 lanes/16B-slot = the 1KB/wave
//    b128 minimum = effectively conflict-free.
__global__ __launch_bounds__(256, 4) void k_fused(
    const float* __restrict__ x, const float* __restrict__ Wm,
    const float* __restrict__ a, const float* __restrict__ efmT,
    const int* __restrict__ mask, float* __restrict__ out) {
    // staging: As fp32 [128][32] (16KB) + Bs fp32 [128][32] (16KB), linear.
    // post-GEMM union: WxL u16 [128][136] = 34816B.
    __shared__ __align__(16) char ubuf[34816];
    float* As  = (float*)ubuf;          // [128*32] fp32, swizzled content
    float* Bsf = As + 4096;             // [128*32] fp32
    u16*   WxL = (u16*)ubuf;            // [c][v] stride 136 (post-GEMM)
    __shared__ float ssl[256], sdl[256], rden[2][128];
    __shared__ int mkl[128];

    const int t = threadIdx.x;
    const int b = blockIdx.x, hp = blockIdx.y;
    const int w = t >> 6, L = t & 63;
    const int wr = w >> 1, wc = w & 1;
    const int lr = L & 15, lg = L >> 4;

    if (t < 128) mkl[t] = mask[b * VV + t];

    // ---- GEMM phase: DMA-staged fp32, convert at frag prep ----
    // DMA round r (0..3), wave w: chunk c = r*4+w stages rows c*8..c*8+7,
    // lane L -> row c*8+(L>>3), 16B at swizzled col chunk (L&7)^((L>>3)&7).
    const int lrow = L >> 3;
    const int scol = ((L & 7) ^ (lrow & 7)) * 4;      // fp32 col of 16B chunk
    const float* gA = x  + ((size_t)b * VV + w * 8 + lrow) * DD + scol;
    const float* gB = Wm + ((size_t)(hp * 128 + w * 8 + lrow)) * DD + scol;
    float* ldsA = As  + w * 256;        // + r*1024 floats (chunk*1KB)
    float* ldsB = Bsf + w * 256;

    f32x4 acc[4][4];
    #pragma unroll
    for (int i = 0; i < 4; ++i)
        #pragma unroll
        for (int j = 0; j < 4; ++j) acc[i][j] = (f32x4){0.f, 0.f, 0.f, 0.f};

    for (int ks = 0; ks < 8; ++ks) {
        #pragma unroll
        for (int r = 0; r < 4; ++r) {   // 8 DMAs, issued back-to-back, async
            gld16(gA + r * 8192 + ks * 32, ldsA + r * 1024);
            gld16(gB + r * 8192 + ks * 32, ldsB + r * 1024);
        }
        __syncthreads();                // drain: all DMAs landed, LDS visible
        const int sw = (lr & 7) << 2;   // read-side XOR (dwords), same involution
        bf16x8 af[4], bfr[4];
        #pragma unroll
        for (int mi = 0; mi < 4; ++mi) {
            const float* rp = As + (wr * 64 + mi * 16 + lr) * 32;
            float4 f0 = *(const float4*)&rp[(lg * 8) ^ sw];
            float4 f1 = *(const float4*)&rp[(lg * 8 + 4) ^ sw];
            unsigned* u = (unsigned*)&af[mi];
            u[0] = pk2(f0.x, f0.y); u[1] = pk2(f0.z, f0.w);
            u[2] = pk2(f1.x, f1.y); u[3] = pk2(f1.z, f1.w);
        }
        #pragma unroll
        for (int ni = 0; ni < 4; ++ni) {
            const float* rp = Bsf + (wc * 64 + ni * 16 + lr) * 32;
            float4 f0 = *(const float4*)&rp[(lg * 8) ^ sw];
            float4 f1 = *(const float4*)&rp[(lg * 8 + 4) ^ sw];
            unsigned* u = (unsigned*)&bfr[ni];
            u[0] = pk2(f0.x, f0.y); u[1] = pk2(f0.z, f0.w);
            u[2] = pk2(f1.x, f1.y); u[3] = pk2(f1.z, f1.w);
        }
        #pragma unroll
        for (int mi = 0; mi < 4; ++mi)
            #pragma unroll
            for (int ni = 0; ni < 4; ++ni)
                acc[mi][ni] = __builtin_amdgcn_mfma_f32_16x16x32_bf16(
                    af[mi], bfr[ni], acc[mi][ni], 0, 0, 0);
        __syncthreads();                // frag reads retired; buffer reusable
    }

    // ---- GEMM epilogue: WxL[c][v] bf16 (union over staging) + masked scores --
    float as_[4], ad_[4];
    #pragma unroll
    for (int ni = 0; ni < 4; ++ni) {
        as_[ni] = a[ni * 16 + lr];
        ad_[ni] = a[64 + ni * 16 + lr];
    }
    float ps[16], pd[16];
    #pragma unroll
    for (int k = 0; k < 16; ++k) { ps[k] = 0.f; pd[k] = 0.f; }
    #pragma unroll
    for (int mi = 0; mi < 4; ++mi) {
        #pragma unroll
        for (int ni = 0; ni < 4; ++ni) {
            const int c  = wc * 64 + ni * 16 + lr;    // hl*64 + d
            const int vb = wr * 64 + mi * 16 + lg * 4;
            unsigned o2[2];
            o2[0] = pk2(acc[mi][ni][0], acc[mi][ni][1]);
            o2[1] = pk2(acc[mi][ni][2], acc[mi][ni][3]);
            #pragma unroll
            for (int r = 0; r < 4; ++r) {
                float v = acc[mi][ni][r];
                ps[mi * 4 + r] = fmaf(v, as_[ni], ps[mi * 4 + r]);
                pd[mi * 4 + r] = fmaf(v, ad_[ni], pd[mi * 4 + r]);
            }
            *(uint2*)&WxL[c * 136 + vb] = *(uint2*)&o2[0];   // ds_write_b64
        }
    }
    #pragma unroll
    for (int k = 0; k < 16; ++k) {
        #pragma unroll
        for (int m = 1; m < 16; m <<= 1) {
            ps[k] += __shfl_xor(ps[k], m);
            pd[k] += __shfl_xor(pd[k], m);
        }
    }
    if (lr == 0) {
        #pragma unroll
        for (int mi = 0; mi < 4; ++mi)
            #pragma unroll
            for (int r = 0; r < 4; ++r) {
                int v = wr * 64 + mi * 16 + lg * 4 + r;
                bool mk = mkl[v] != 0;
                ssl[wc * 128 + v] = mk ? -INFINITY : ps[mi * 4 + r];
                sdl[wc * 128 + v] = mk ? -INFINITY : pd[mi * 4 + r];
            }
    }
    __syncthreads();   // WxL + scores ready

    // ---- Attention: P straight into A-fragments, per head ----
    const int j0 = w * 32 + lr;          // mi=0 row; mi=1 row = j0+16
    for (int hl = 0; hl < 2; ++hl) {
        const int h = hp * 2 + hl;
        const float sdj0 = sdl[hl * 128 + j0];
        const float sdj1 = sdl[hl * 128 + j0 + 16];
        const float* ef0 = efmT + ((size_t)h * VV + j0) * VV;
        const float* ef1 = ef0 + 16 * VV;
        bf16x8 af2[2][4];
        float ps0 = 0.f, ps1 = 0.f;
        #pragma unroll
        for (int ks = 0; ks < 4; ++ks) {
            const int i0 = ks * 32 + lg * 8;
            float sv[8], ev0[8], ev1[8];
            *(float4*)&sv[0]  = *(const float4*)&ssl[hl * 128 + i0];
            *(float4*)&sv[4]  = *(const float4*)&ssl[hl * 128 + i0 + 4];
            *(float4*)&ev0[0] = *(const float4*)(ef0 + i0);
            *(float4*)&ev0[4] = *(const float4*)(ef0 + i0 + 4);
            *(float4*)&ev1[0] = *(const float4*)(ef1 + i0);
            *(float4*)&ev1[4] = *(const float4*)(ef1 + i0 + 4);
            float p0[8], p1[8];
            #pragma unroll
            for (int u = 0; u < 8; ++u) {
                float e0 = sv[u] + sdj0 + ev0[u];
                float e1 = sv[u] + sdj1 + ev1[u];
                e0 = fmaxf(e0, 0.2f * e0);     // leaky relu
                e1 = fmaxf(e1, 0.2f * e1);
                p0[u] = __expf(e0); ps0 += p0[u];   // exp(-inf)=0 masks
                p1[u] = __expf(e1); ps1 += p1[u];
            }
            unsigned* a0 = (unsigned*)&af2[0][ks];
            unsigned* a1 = (unsigned*)&af2[1][ks];
            a0[0] = pk2(p0[0], p0[1]); a0[1] = pk2(p0[2], p0[3]);
            a0[2] = pk2(p0[4], p0[5]); a0[3] = pk2(p0[6], p0[7]);
            a1[0] = pk2(p1[0], p1[1]); a1[1] = pk2(p1[2], p1[3]);
            a1[2] = pk2(p1[4], p1[5]); a1[3] = pk2(p1[6], p1[7]);
        }
        // denom over all 128 i: lanes sharing j differ only in lg (bits 4,5)
        ps0 += __shfl_xor(ps0, 16); ps0 += __shfl_xor(ps0, 32);
        ps1 += __shfl_xor(ps1, 16); ps1 += __shfl_xor(ps1, 32);
        if (lg == 0) {
            rden[hl][j0]      = ps0 > 0.f ? 1.f / ps0 : 0.f;
            rden[hl][j0 + 16] = ps1 > 0.f ? 1.f / ps1 : 0.f;
        }
        // rden rows w*32..w*32+31: written and read by THIS wave only.

        f32x4 acc2[2][4];
        #pragma unroll
        for (int mi = 0; mi < 2; ++mi)
            #pragma unroll
            for (int ni = 0; ni < 4; ++ni) acc2[mi][ni] = (f32x4){0.f, 0.f, 0.f, 0.f};
        #pragma unroll
        for (int ks = 0; ks < 4; ++ks) {
            const int kk = ks * 32 + lg * 8;
            #pragma unroll
            for (int ni = 0; ni < 4; ++ni) {
                bf16x8 bf2 = *(const bf16x8*)&WxL[(hl * 64 + ni * 16 + lr) * 136 + kk];
                acc2[0][ni] = __builtin_amdgcn_mfma_f32_16x16x32_bf16(
                    af2[0][ks], bf2, acc2[0][ni], 0, 0, 0);
                acc2[1][ni] = __builtin_amdgcn_mfma_f32_16x16x32_bf16(
                    af2[1][ks], bf2, acc2[1][ni], 0, 0, 0);
            }
        }

        #pragma unroll
        for (int mi = 0; mi < 2; ++mi)
            #pragma unroll
            for (int ni = 0; ni < 4; ++ni) {
                const int dcol = ni * 16 + lr;
                const int jb   = w * 32 + mi * 16 + lg * 4;
                float* op = out + ((size_t)b * VV + jb) * DD + h * DHH + dcol;
                #pragma unroll
                for (int r = 0; r < 4; ++r) {
                    float v = acc2[mi][ni][r] * rden[hl][jb + r];
                    // ELU: __expf(v)-1 (2 insts) instead of OCML expm1f.
                    v = v > 0.f ? v : (__expf(v) - 1.0f);
                    op[(size_t)r * DD] = v;
                }
            }
    }
}

extern "C" void kernel_launch(void* const* d_in, const int* in_sizes, int n_in,
                              void* d_out, int out_size, void* d_ws, size_t ws_size,
                              hipStream_t stream) {
    const float* x    = (const float*)d_in[0];
    const int*   adj  = (const int*)d_in[1];
    const float* ea   = (const float*)d_in[2];
    const int*   mask = (const int*)d_in[3];
    const float* Wm   = (const float*)d_in[4];
    const float* a    = (const float*)d_in[5];
    const float* Ew   = (const float*)d_in[6];
    float* out = (float*)d_out;

    float* efmT = (float*)d_ws;   // [H][j][i] fp32, 256 KiB

    k_ef<<<dim3(4, 4, HH), 256, 0, stream>>>(ea, Ew, adj, efmT);
    k_fused<<<dim3(BB, 2), 256, 0, stream>>>(x, Wm, a, efmT, mask, out);
}